// Round 1
// 271.213 us; speedup vs baseline: 1.0413x; 1.0413x over previous
//
#include <hip/hip_runtime.h>
#include <hip/hip_bf16.h>

// B=8, N=4096 (=64x64 spatial), C=768.
// Y = ReFFT2_spatial(X) @ (proj_w @ Wv)^T + proj_b,  Wv = qkv_w[1536:2304].
// K0: tw_init — precompute per-lane twiddle MFMA fragments (TwA 12KB, TwB 16KB)
// K1 (merged into K2's grid, dispatched FIRST): M = proj_w @ Wv  (bf16)
// K2: pass A twiddle-MFMA, Hermitian store k2=0..32
// K3: pass B twiddle-MFMA, emits k2 and 64-k2
// K4: Y = Xf @ M^T + b   (32x32x16 MFMA, BK=64, XOR-swizzled staging)

typedef __bf16 bf16x8 __attribute__((ext_vector_type(8)));
typedef __bf16 bf16x4 __attribute__((ext_vector_type(4)));
typedef float f32x4 __attribute__((ext_vector_type(4)));
typedef float f32x16 __attribute__((ext_vector_type(16)));
typedef unsigned short ushort_t;
typedef unsigned int uint_t;

typedef __attribute__((address_space(3))) unsigned int lds_u32;
typedef __attribute__((address_space(1))) unsigned int glob_u32;

__device__ __forceinline__ void gl_lds16(const void* g, void* l) {
  __builtin_amdgcn_global_load_lds((const glob_u32*)g, (lds_u32*)l, 16, 0, 0);
}

__device__ __forceinline__ ushort_t f2bf(float f) {
  union { __hip_bfloat16 h; ushort_t s; } cv;
  cv.h = __float2bfloat16(f);
  return cv.s;
}

__device__ __forceinline__ bf16x8 ld_frag(const ushort_t* p) {  // 8B-aligned
  union { bf16x8 v; bf16x4 h[2]; } r;
  r.h[0] = *(const bf16x4*)p;
  r.h[1] = *(const bf16x4*)(p + 4);
  return r.v;
}

// ---------- K0: twiddle fragment tables (computed once, loaded by K2/K3) ----
// TwA layout: [cs(2)][mt(3)][ks(2)][lane(64)] bf16x8   (768 frags, 12288 B)
// TwB layout: [cs(2)][wm(2)][mt(2)][ks(2)][lane(64)] bf16x8 (1024 frags, 16384 B)
// value[e] = trig(2*pi*(m*(k0+e) mod 64)/64), m/k0 per the consumer's lane map.
__global__ __launch_bounds__(256) void tw_init(ushort_t* __restrict__ TwA,
                                               ushort_t* __restrict__ TwB) {
  const int id = blockIdx.x * 256 + threadIdx.x;   // 0..1791
  int m, k0, sn;
  ushort_t* out;
  if (id < 768) {
    int r = id % 384, cs = id / 384;
    int l = r & 63, ks = (r >> 6) & 1, mt = r >> 7;
    m = mt * 16 + (l & 15);
    k0 = ks * 32 + (l >> 4) * 8;
    sn = cs;
    out = TwA + id * 8;
  } else {
    int j = id - 768;
    int r = j % 512, cs = j / 512;
    int l = r & 63, ks = (r >> 6) & 1, mt = (r >> 7) & 1, wm = r >> 8;
    m = wm * 32 + mt * 16 + (l & 15);
    k0 = ks * 32 + (l >> 4) * 8;
    sn = cs;
    out = TwB + j * 8;
  }
#pragma unroll
  for (int e = 0; e < 8; ++e) {
    int ph = (m * (k0 + e)) & 63;
    float a = (float)ph * 0.09817477042468104f;  // 2*pi/64
    out[e] = f2bf(sn ? __sinf(a) : __cosf(a));
  }
}

// ---------- K2 (+K1): M precompute on by<6 (dispatch-first); pass A on by>=6 --
__global__ __launch_bounds__(256) void fft_a_pre(const float* __restrict__ X,
                                                 const float* __restrict__ P,
                                                 const float* __restrict__ Q,
                                                 __hip_bfloat16* __restrict__ Ar,
                                                 __hip_bfloat16* __restrict__ Ai,
                                                 __hip_bfloat16* __restrict__ Mb,
                                                 const ushort_t* __restrict__ TwA) {
  __shared__ ushort_t smem[9728];     // 19456 B; both paths overlay into this
  const int t = threadIdx.x;
  const int c0 = blockIdx.x * 128;
  const int w = t >> 6, l = t & 63;
  const int lm = l & 15, lq = l >> 4;

  if (blockIdx.y >= 6) {              // ---------------- FFT pass A ----------------
    ushort_t* Xs = smem;              // [c][n2] stride 68 (8704 ush)
    ushort_t* Ep = smem;              // [k2][c] stride 136 — overlays Xs after use
    const int s = blockIdx.y - 6;     // b*64 + n1
    const float* src = X + (size_t)s * 64 * 768 + c0;
    // twiddle fragments: 12 coalesced 16B loads (L2-resident), issued early
    const bf16x8* twa = (const bf16x8*)TwA;
    bf16x8 afc[3][2], afs[3][2];
#pragma unroll
    for (int mt = 0; mt < 3; ++mt)
#pragma unroll
      for (int ks = 0; ks < 2; ++ks) {
        afc[mt][ks] = twa[mt * 128 + ks * 64 + l];
        afs[mt][ks] = twa[384 + mt * 128 + ks * 64 + l];
      }
    // X staging: 8 dwordx4 loads/thread (2 rows x 4 cols per iter), transpose pack
#pragma unroll
    for (int it = 0; it < 4; ++it) {
      const int pr = it * 8 + (t >> 5);      // n2 pair 0..31
      const int c = (t & 31) * 4;
      const float* rp = src + (size_t)(2 * pr) * 768 + c;
      f32x4 f0 = *(const f32x4*)rp;
      f32x4 f1 = *(const f32x4*)(rp + 768);
#pragma unroll
      for (int j = 0; j < 4; ++j) {
        uint_t pk = (uint_t)f2bf(f0[j]) | ((uint_t)f2bf(f1[j]) << 16);
        *(uint_t*)&Xs[(c + j) * 68 + 2 * pr] = pk;
      }
    }
    __syncthreads();
    f32x4 accr[3][2] = {}, acci[3][2] = {};
#pragma unroll
    for (int ks = 0; ks < 2; ++ks) {
      bf16x8 bf[2];
#pragma unroll
      for (int nt = 0; nt < 2; ++nt) {
        int c = w * 32 + nt * 16 + lm;
        bf[nt] = ld_frag(&Xs[c * 68 + ks * 32 + lq * 8]);
      }
#pragma unroll
      for (int mt = 0; mt < 3; ++mt)
#pragma unroll
        for (int nt = 0; nt < 2; ++nt) {
          accr[mt][nt] = __builtin_amdgcn_mfma_f32_16x16x32_bf16(afc[mt][ks], bf[nt], accr[mt][nt], 0, 0, 0);
          acci[mt][nt] = __builtin_amdgcn_mfma_f32_16x16x32_bf16(afs[mt][ks], bf[nt], acci[mt][nt], 0, 0, 0);
        }
    }
#pragma unroll
    for (int arr = 0; arr < 2; ++arr) {
      __syncthreads();                // Xs dead after this point on arr=0
#pragma unroll
      for (int mt = 0; mt < 3; ++mt)
#pragma unroll
        for (int nt = 0; nt < 2; ++nt)
#pragma unroll
          for (int r = 0; r < 4; ++r) {
            int row = mt * 16 + lq * 4 + r;
            int col = w * 32 + nt * 16 + lm;
            float v = arr ? acci[mt][nt][r] : accr[mt][nt][r];
            Ep[row * 136 + col] = f2bf(v);
          }
      __syncthreads();
      __hip_bfloat16* dst = arr ? Ai : Ar;
#pragma unroll
      for (int it = 0; it < 3; ++it) {
        int idx = it * 256 + t;       // uint4 units; keep rows <=32
        int row = idx >> 4, cq = (idx & 15) * 8;
        if (row <= 32) {
          uint4 v = *(const uint4*)&Ep[row * 136 + cq];
          *(uint4*)&dst[(size_t)(s * 64 + row) * 768 + c0 + cq] = v;
        }
      }
    }
  } else {                            // ---------------- precompute M ----------------
    ushort_t* As = smem;              // [i][d] stride 40 (5120 ush)
    ushort_t* Bs = smem + 5120;       // [c][d] stride 36 (4608 ush)
    const int i0 = blockIdx.y * 128;
    const int wm = w & 1, wn = w >> 1;
    f32x4 acc[4][4] = {};
    for (int kt = 0; kt < 24; ++kt) {
      const int k0 = kt * 32;
      {
        int e = t * 16, row = e >> 5, dc = e & 16;
        const float* src = &P[(size_t)(i0 + row) * 768 + k0 + dc];
        float4 f0 = *(const float4*)&src[0], f1 = *(const float4*)&src[4];
        float4 f2 = *(const float4*)&src[8], f3 = *(const float4*)&src[12];
        union { ushort_t u[8]; uint4 v; } pk0, pk1;
        pk0.u[0] = f2bf(f0.x); pk0.u[1] = f2bf(f0.y); pk0.u[2] = f2bf(f0.z); pk0.u[3] = f2bf(f0.w);
        pk0.u[4] = f2bf(f1.x); pk0.u[5] = f2bf(f1.y); pk0.u[6] = f2bf(f1.z); pk0.u[7] = f2bf(f1.w);
        pk1.u[0] = f2bf(f2.x); pk1.u[1] = f2bf(f2.y); pk1.u[2] = f2bf(f2.z); pk1.u[3] = f2bf(f2.w);
        pk1.u[4] = f2bf(f3.x); pk1.u[5] = f2bf(f3.y); pk1.u[6] = f2bf(f3.z); pk1.u[7] = f2bf(f3.w);
        *(uint4*)&As[row * 40 + dc] = pk0.v;
        *(uint4*)&As[row * 40 + dc + 8] = pk1.v;
      }
      // Q staging: 4 dwordx4 loads/thread (2 rows x 4 cols per iter)
#pragma unroll
      for (int it = 0; it < 2; ++it) {
        const int pr = it * 8 + (t >> 5);    // k pair 0..15
        const int c = (t & 31) * 4;
        const float* qp = Q + (size_t)(1536 + k0 + 2 * pr) * 768 + c0 + c;
        f32x4 q0 = *(const f32x4*)qp;
        f32x4 q1 = *(const f32x4*)(qp + 768);
#pragma unroll
        for (int j = 0; j < 4; ++j) {
          uint_t pk = (uint_t)f2bf(q0[j]) | ((uint_t)f2bf(q1[j]) << 16);
          *(uint_t*)&Bs[(c + j) * 36 + 2 * pr] = pk;
        }
      }
      __syncthreads();
      bf16x8 af[4], bfr[4];
#pragma unroll
      for (int mt = 0; mt < 4; ++mt)
        af[mt] = ld_frag(&As[(wm * 64 + mt * 16 + lm) * 40 + lq * 8]);
#pragma unroll
      for (int nt = 0; nt < 4; ++nt)
        bfr[nt] = ld_frag(&Bs[(wn * 64 + nt * 16 + lm) * 36 + lq * 8]);
#pragma unroll
      for (int mt = 0; mt < 4; ++mt)
#pragma unroll
        for (int nt = 0; nt < 4; ++nt)
          acc[mt][nt] = __builtin_amdgcn_mfma_f32_16x16x32_bf16(af[mt], bfr[nt], acc[mt][nt], 0, 0, 0);
      __syncthreads();
    }
#pragma unroll
    for (int nt = 0; nt < 4; ++nt) {
      const int col = c0 + wn * 64 + nt * 16 + lm;
#pragma unroll
      for (int mt = 0; mt < 4; ++mt) {
        const int rbase = i0 + wm * 64 + mt * 16 + lq * 4;
#pragma unroll
        for (int r = 0; r < 4; ++r)
          Mb[(size_t)(rbase + r) * 768 + col] = __float2bfloat16(acc[mt][nt][r]);
      }
    }
  }
}

// ---------- K3: pass B (MFMA), contract n1. Pair outputs k2 / 64-k2. ----------
__global__ __launch_bounds__(256) void fft_b_mfma(const __hip_bfloat16* __restrict__ Ar,
                                                  const __hip_bfloat16* __restrict__ Ai,
                                                  __hip_bfloat16* __restrict__ Xf,
                                                  const ushort_t* __restrict__ TwB) {
  __shared__ ushort_t smem[17408];    // Rs 8704 | Is 8704 ; Ep overlays Rs
  ushort_t* Rs = smem;
  ushort_t* Is = smem + 8704;
  ushort_t* Ep = smem;                // [k1][c] stride 136, used after Rs dead
  const int t = threadIdx.x;
  const int bz = blockIdx.y;          // b*33 + k2
  const int b = bz / 33, k2 = bz % 33;
  const int c0 = blockIdx.x * 128;
  const ushort_t* ar = (const ushort_t*)Ar + ((size_t)(b * 64) * 64 + k2) * 768 + c0;
  const ushort_t* ai = (const ushort_t*)Ai + ((size_t)(b * 64) * 64 + k2) * 768 + c0;
  const size_t n1s = (size_t)64 * 768;
  const int w = t >> 6, l = t & 63;
  const int wm = w & 1, wn = w >> 1;
  const int lm = l & 15, lq = l >> 4;
  // twiddle fragments: 8 coalesced 16B loads (L2-resident), issued early
  const bf16x8* twb = (const bf16x8*)TwB;
  bf16x8 afc[2][2], afs[2][2];
#pragma unroll
  for (int mt = 0; mt < 2; ++mt)
#pragma unroll
    for (int ks = 0; ks < 2; ++ks) {
      afc[mt][ks] = twb[wm * 256 + mt * 128 + ks * 64 + l];
      afs[mt][ks] = twb[512 + wm * 256 + mt * 128 + ks * 64 + l];
    }
  // Ar/Ai staging: 16 dwordx2 loads/thread total (vs 64 u16 loads), repack in regs
#pragma unroll
  for (int it = 0; it < 4; ++it) {
    const int pr = it * 8 + (t >> 5);        // n1 pair 0..31
    const int c = (t & 31) * 4;
    const size_t o0 = (size_t)(2 * pr) * n1s + c;
    uint2 va = *(const uint2*)&ar[o0];
    uint2 vb = *(const uint2*)&ar[o0 + n1s];
    uint2 ia = *(const uint2*)&ai[o0];
    uint2 ib = *(const uint2*)&ai[o0 + n1s];
    uint_t r0 = (va.x & 0xffffu) | (vb.x << 16);
    uint_t r1 = (va.x >> 16) | (vb.x & 0xffff0000u);
    uint_t r2 = (va.y & 0xffffu) | (vb.y << 16);
    uint_t r3 = (va.y >> 16) | (vb.y & 0xffff0000u);
    *(uint_t*)&Rs[(c + 0) * 68 + 2 * pr] = r0;
    *(uint_t*)&Rs[(c + 1) * 68 + 2 * pr] = r1;
    *(uint_t*)&Rs[(c + 2) * 68 + 2 * pr] = r2;
    *(uint_t*)&Rs[(c + 3) * 68 + 2 * pr] = r3;
    uint_t s0 = (ia.x & 0xffffu) | (ib.x << 16);
    uint_t s1 = (ia.x >> 16) | (ib.x & 0xffff0000u);
    uint_t s2 = (ia.y & 0xffffu) | (ib.y << 16);
    uint_t s3 = (ia.y >> 16) | (ib.y & 0xffff0000u);
    *(uint_t*)&Is[(c + 0) * 68 + 2 * pr] = s0;
    *(uint_t*)&Is[(c + 1) * 68 + 2 * pr] = s1;
    *(uint_t*)&Is[(c + 2) * 68 + 2 * pr] = s2;
    *(uint_t*)&Is[(c + 3) * 68 + 2 * pr] = s3;
  }
  __syncthreads();
  f32x4 accC[2][4] = {}, accS[2][4] = {};
#pragma unroll
  for (int ks = 0; ks < 2; ++ks) {
    bf16x8 bR[4], bI[4];
#pragma unroll
    for (int nt = 0; nt < 4; ++nt) {
      int c = wn * 64 + nt * 16 + lm;
      int kb = ks * 32 + lq * 8;
      bR[nt] = ld_frag(&Rs[c * 68 + kb]);
      bI[nt] = ld_frag(&Is[c * 68 + kb]);
    }
#pragma unroll
    for (int mt = 0; mt < 2; ++mt)
#pragma unroll
      for (int nt = 0; nt < 4; ++nt) {
        accC[mt][nt] = __builtin_amdgcn_mfma_f32_16x16x32_bf16(afc[mt][ks], bR[nt], accC[mt][nt], 0, 0, 0);
        accS[mt][nt] = __builtin_amdgcn_mfma_f32_16x16x32_bf16(afs[mt][ks], bI[nt], accS[mt][nt], 0, 0, 0);
      }
  }
  const int nout = (k2 >= 1 && k2 <= 31) ? 2 : 1;
  for (int o = 0; o < nout; ++o) {
    __syncthreads();                   // Rs/Is dead from here
#pragma unroll
    for (int mt = 0; mt < 2; ++mt)
#pragma unroll
      for (int nt = 0; nt < 4; ++nt)
#pragma unroll
        for (int r = 0; r < 4; ++r) {
          int row = wm * 32 + mt * 16 + lq * 4 + r;   // k1
          int col = wn * 64 + nt * 16 + lm;           // c
          float v = o ? (accC[mt][nt][r] + accS[mt][nt][r])
                      : (accC[mt][nt][r] - accS[mt][nt][r]);
          Ep[row * 136 + col] = f2bf(v);
        }
    __syncthreads();
    const int k2o = o ? (64 - k2) : k2;
#pragma unroll
    for (int it = 0; it < 4; ++it) {
      int idx = it * 256 + t;
      int k1 = idx >> 4, cq = (idx & 15) * 8;
      uint4 v = *(const uint4*)&Ep[k1 * 136 + cq];
      *(uint4*)&Xf[((size_t)b * 4096 + k1 * 64 + k2o) * 768 + c0 + cq] = v;
    }
  }
}

// ---------- K4: Y[m,n] = sum_k Xf[m,k]*Mb[n,k] + bias[n] ----------
// 128x128 tile, BK=64, 32x32x16 MFMA, XOR-swizzled global_load_lds staging.
__global__ __launch_bounds__(256) void gemm_bt(const __hip_bfloat16* __restrict__ A,
                                               const __hip_bfloat16* __restrict__ B,
                                               const float* __restrict__ bias,
                                               float* __restrict__ C) {
  __shared__ ushort_t As[128 * 64];
  __shared__ ushort_t Bs[128 * 64];
  const int t = threadIdx.x, w = t >> 6, l = t & 63;
  // XCD swizzle: 6 n-tiles sharing an A panel on one XCD (round-robin L%8).
  const int L = blockIdx.x + blockIdx.y * 6;
  const int s = L >> 3, xcd = L & 7;
  const int n0 = (s % 6) * 128;
  const int m0 = ((s / 6) * 8 + xcd) * 128;
  const int wm = w & 1, wn = w >> 1;
  f32x16 acc[2][2] = {};
  // staging lane constants: row-in-group, swizzled source chunk
  const int srow = l >> 3;                       // 0..7
  const int schunk = (l & 7) ^ srow;             // global 8-elem chunk
  const int lr = l & 31, lh = l >> 5;            // MFMA row / k-half
  for (int kt = 0; kt < 12; ++kt) {
    const int k0 = kt * 64;
#pragma unroll
    for (int i = 0; i < 4; ++i) {
      const int rbase = w * 32 + i * 8;          // wave-uniform
      const int row = rbase + srow;
      gl_lds16(&A[(size_t)(m0 + row) * 768 + k0 + schunk * 8], &As[rbase * 64]);
      gl_lds16(&B[(size_t)(n0 + row) * 768 + k0 + schunk * 8], &Bs[rbase * 64]);
    }
    __syncthreads();
#pragma unroll
    for (int ks = 0; ks < 4; ++ks) {
      bf16x8 af[2], bf[2];
#pragma unroll
      for (int mt = 0; mt < 2; ++mt) {
        int row = wm * 64 + mt * 32 + lr;
        int ch = (ks * 2 + lh) ^ (lr & 7);       // un-swizzle
        af[mt] = *(const bf16x8*)&As[row * 64 + ch * 8];
      }
#pragma unroll
      for (int nt = 0; nt < 2; ++nt) {
        int row = wn * 64 + nt * 32 + lr;
        int ch = (ks * 2 + lh) ^ (lr & 7);
        bf[nt] = *(const bf16x8*)&Bs[row * 64 + ch * 8];
      }
#pragma unroll
      for (int mt = 0; mt < 2; ++mt)
#pragma unroll
        for (int nt = 0; nt < 2; ++nt)
          acc[mt][nt] = __builtin_amdgcn_mfma_f32_32x32x16_bf16(af[mt], bf[nt], acc[mt][nt], 0, 0, 0);
    }
    __syncthreads();
  }
  // epilogue: C/D layout 32x32: col=lane&31, row=(reg&3)+8*(reg>>2)+4*(lane>>5)
#pragma unroll
  for (int nt = 0; nt < 2; ++nt) {
    const int col = n0 + wn * 64 + nt * 32 + lr;
    const float bv = bias[col];
#pragma unroll
    for (int mt = 0; mt < 2; ++mt) {
      const int rb = m0 + wm * 64 + mt * 32 + 4 * lh;
#pragma unroll
      for (int reg = 0; reg < 16; ++reg) {
        const int row = rb + (reg & 3) + 8 * (reg >> 2);
        C[(size_t)row * 768 + col] = acc[mt][nt][reg] + bv;
      }
    }
  }
}

extern "C" void kernel_launch(void* const* d_in, const int* in_sizes, int n_in,
                              void* d_out, int out_size, void* d_ws, size_t ws_size,
                              hipStream_t stream) {
  const float* x      = (const float*)d_in[0];  // [8,4096,768]
  const float* qkv_w  = (const float*)d_in[1];  // [2304,768]
  const float* proj_w = (const float*)d_in[2];  // [768,768]
  const float* proj_b = (const float*)d_in[3];  // [768]
  float* out = (float*)d_out;                   // [8,4096,768] fp32

  char* ws = (char*)d_ws;
  const size_t MB_BYTES = (size_t)768 * 768 * 2;
  const size_t ARR_BYTES = (size_t)8 * 4096 * 768 * 2;
  __hip_bfloat16* Mb = (__hip_bfloat16*)ws;
  __hip_bfloat16* Ar = (__hip_bfloat16*)(ws + MB_BYTES);
  __hip_bfloat16* Ai = (__hip_bfloat16*)(ws + MB_BYTES + ARR_BYTES);
  __hip_bfloat16* Xf = (__hip_bfloat16*)(ws + MB_BYTES + 2 * ARR_BYTES);
  // Twiddle tables live in dead rows (k2=40..63 of s=0 block) of Ar:
  // fft_a only writes rows <=32 per 64-row group; fft_b only reads k2<=32.
  ushort_t* TwA = (ushort_t*)((char*)Ar + 61440);            // 12288 B
  ushort_t* TwB = (ushort_t*)((char*)Ar + 61440 + 12288);    // 16384 B (ends 90112 < 98304)

  tw_init<<<dim3(7), 256, 0, stream>>>(TwA, TwB);
  fft_a_pre<<<dim3(6, 518), 256, 0, stream>>>(x, proj_w, qkv_w, Ar, Ai, Mb, TwA);
  fft_b_mfma<<<dim3(6, 264), 256, 0, stream>>>(Ar, Ai, Xf, TwB);
  gemm_bt<<<dim3(6, 256), 256, 0, stream>>>(Xf, Mb, proj_b, out);
}

// Round 2
// 255.219 us; speedup vs baseline: 1.1065x; 1.0627x over previous
//
#include <hip/hip_runtime.h>
#include <hip/hip_bf16.h>

// B=8, N=4096 (=64x64 spatial), C=768.
// Y = ReFFT2_spatial(X) @ (proj_w @ Wv)^T + proj_b,  Wv = qkv_w[1536:2304].
// K0 prep: twiddle fragment tables + Pb (bf16 proj_w) + Qb (bf16 Wv^T)
// K2: pass A twiddle-MFMA, Hermitian store k2=0..32 (pure FFT now)
// K3: by<6 = M = Pb @ Qb^T (gemm_bt-style, gl_lds staging); by>=6 = FFT pass B
// K4: Y = Xf @ M^T + b   (32x32x16 MFMA, BK=64, XOR-swizzled staging)

typedef __bf16 bf16x8 __attribute__((ext_vector_type(8)));
typedef __bf16 bf16x4 __attribute__((ext_vector_type(4)));
typedef float f32x4 __attribute__((ext_vector_type(4)));
typedef float f32x16 __attribute__((ext_vector_type(16)));
typedef unsigned short ushort_t;
typedef unsigned int uint_t;

typedef __attribute__((address_space(3))) unsigned int lds_u32;
typedef __attribute__((address_space(1))) unsigned int glob_u32;

__device__ __forceinline__ void gl_lds16(const void* g, void* l) {
  __builtin_amdgcn_global_load_lds((const glob_u32*)g, (lds_u32*)l, 16, 0, 0);
}

__device__ __forceinline__ ushort_t f2bf(float f) {
  union { __hip_bfloat16 h; ushort_t s; } cv;
  cv.h = __float2bfloat16(f);
  return cv.s;
}

__device__ __forceinline__ bf16x8 ld_frag(const ushort_t* p) {  // 8B-aligned
  union { bf16x8 v; bf16x4 h[2]; } r;
  r.h[0] = *(const bf16x4*)p;
  r.h[1] = *(const bf16x4*)(p + 4);
  return r.v;
}

// Swizzled fragment read: row-major [row][dword d] with d stored at d^sel2.
// D0 = original starting dword (multiple of 4), sel2 = ((row>>4)&7)<<1.
__device__ __forceinline__ bf16x8 ld_swz(const ushort_t* rowp, int D0, int sel2) {
  union { bf16x8 v; bf16x4 h[2]; } r;
  r.h[0] = *(const bf16x4*)(rowp + 2 * (D0 ^ sel2));
  r.h[1] = *(const bf16x4*)(rowp + 2 * ((D0 + 2) ^ sel2));
  return r.v;
}

// ---------- K0: twiddle tables + bf16 weight prep ----------
// TwA: [cs(2)][mt(3)][ks(2)][lane(64)] bf16x8   (768 frags, 12288 B)
// TwB: [cs(2)][wm(2)][mt(2)][ks(2)][lane(64)] bf16x8 (1024 frags, 16384 B)
// Pb:  bf16 proj_w [768][768] (straight convert)
// Qb:  bf16 Wv^T  [c=768][k=768]  (transpose of qkv_w rows 1536..2303)
__global__ __launch_bounds__(256) void prep(const float* __restrict__ P,
                                            const float* __restrict__ Q,
                                            ushort_t* __restrict__ TwA,
                                            ushort_t* __restrict__ TwB,
                                            ushort_t* __restrict__ Pb,
                                            ushort_t* __restrict__ Qb) {
  __shared__ ushort_t Ts[4608];                  // 64x72 transpose tile
  const int t = threadIdx.x;
  if (blockIdx.x < 7) {                          // ---- twiddle tables ----
    const int id = blockIdx.x * 256 + t;         // 0..1791
    int m, k0, sn;
    ushort_t* out;
    if (id < 768) {
      int r = id % 384, cs = id / 384;
      int l = r & 63, ks = (r >> 6) & 1, mt = r >> 7;
      m = mt * 16 + (l & 15);
      k0 = ks * 32 + (l >> 4) * 8;
      sn = cs;
      out = TwA + id * 8;
    } else {
      int j = id - 768;
      int r = j % 512, cs = j / 512;
      int l = r & 63, ks = (r >> 6) & 1, mt = (r >> 7) & 1, wm = r >> 8;
      m = wm * 32 + mt * 16 + (l & 15);
      k0 = ks * 32 + (l >> 4) * 8;
      sn = cs;
      out = TwB + j * 8;
    }
#pragma unroll
    for (int e = 0; e < 8; ++e) {
      int ph = (m * (k0 + e)) & 63;
      float a = (float)ph * 0.09817477042468104f;  // 2*pi/64
      out[e] = f2bf(sn ? __sinf(a) : __cosf(a));
    }
  } else if (blockIdx.x < 151) {                 // ---- Qb transpose (144 64x64 tiles) ----
    const int tile = blockIdx.x - 7;
    const int ti = tile / 12, tj = tile % 12;    // ti: k-tile, tj: c-tile
    const int r0 = t >> 4, c4 = (t & 15) * 4;
#pragma unroll
    for (int rr = 0; rr < 4; ++rr) {
      const int k = ti * 64 + r0 + rr * 16;
      f32x4 v = *(const f32x4*)&Q[(size_t)(1536 + k) * 768 + tj * 64 + c4];
#pragma unroll
      for (int j = 0; j < 4; ++j)
        Ts[(c4 + j) * 72 + r0 + rr * 16] = f2bf(v[j]);
    }
    __syncthreads();
    const int co = t >> 2, kq = (t & 3) * 16;
    uint4 v0 = *(const uint4*)&Ts[co * 72 + kq];
    uint4 v1 = *(const uint4*)&Ts[co * 72 + kq + 8];
    ushort_t* dst = Qb + (size_t)(tj * 64 + co) * 768 + ti * 64 + kq;
    *(uint4*)&dst[0] = v0;
    *(uint4*)&dst[8] = v1;
  } else {                                       // ---- Pb convert (288 blocks) ----
    const int cid = blockIdx.x - 151;
    const size_t off = (size_t)cid * 2048 + t * 8;
    f32x4 f0 = *(const f32x4*)&P[off];
    f32x4 f1 = *(const f32x4*)&P[off + 4];
    union { ushort_t u[8]; uint4 v; } pk;
#pragma unroll
    for (int j = 0; j < 4; ++j) { pk.u[j] = f2bf(f0[j]); pk.u[4 + j] = f2bf(f1[j]); }
    *(uint4*)&Pb[off] = pk.v;
  }
}

// ---------- K2: FFT pass A (pure). Swizzled staging. ----------
__global__ __launch_bounds__(256) void fft_a_pre(const float* __restrict__ X,
                                                 __hip_bfloat16* __restrict__ Ar,
                                                 __hip_bfloat16* __restrict__ Ai,
                                                 const ushort_t* __restrict__ TwA) {
  __shared__ ushort_t smem[9728];     // 19456 B
  ushort_t* Xs = smem;                // [c][d swz] stride 68 (8704 ush)
  ushort_t* Ep = smem;                // [k2][c] stride 136 — overlays Xs after use
  const int t = threadIdx.x;
  const int c0 = blockIdx.x * 128;
  const int w = t >> 6, l = t & 63;
  const int lm = l & 15, lq = l >> 4;
  const int s = blockIdx.y;           // b*64 + n1
  const float* src = X + (size_t)s * 64 * 768 + c0;
  // twiddle fragments: 12 coalesced 16B loads (L2-resident)
  const bf16x8* twa = (const bf16x8*)TwA;
  bf16x8 afc[3][2], afs[3][2];
#pragma unroll
  for (int mt = 0; mt < 3; ++mt)
#pragma unroll
    for (int ks = 0; ks < 2; ++ks) {
      afc[mt][ks] = twa[mt * 128 + ks * 64 + l];
      afs[mt][ks] = twa[384 + mt * 128 + ks * 64 + l];
    }
  // X staging: 8 dwordx4 loads/thread, transpose pack, atom-swizzled LDS writes
#pragma unroll
  for (int it = 0; it < 4; ++it) {
    const int pr = it * 8 + (t >> 5);        // n2-pair dword 0..31
    const int c = (t & 31) * 4;
    const float* rp = src + (size_t)(2 * pr) * 768 + c;
    f32x4 f0 = *(const f32x4*)rp;
    f32x4 f1 = *(const f32x4*)(rp + 768);
#pragma unroll
    for (int j = 0; j < 4; ++j) {
      uint_t pk = (uint_t)f2bf(f0[j]) | ((uint_t)f2bf(f1[j]) << 16);
      const int row = c + j;
      const int d = pr ^ (((row >> 4) & 7) << 1);
      *(uint_t*)&Xs[row * 68 + 2 * d] = pk;
    }
  }
  __syncthreads();
  f32x4 accr[3][2] = {}, acci[3][2] = {};
#pragma unroll
  for (int ks = 0; ks < 2; ++ks) {
    bf16x8 bf[2];
#pragma unroll
    for (int nt = 0; nt < 2; ++nt) {
      int c = w * 32 + nt * 16 + lm;
      int sel2 = ((c >> 4) & 7) << 1;        // uniform per fragment (c 16-aligned)
      bf[nt] = ld_swz(&Xs[c * 68], ks * 16 + lq * 4, sel2);
    }
#pragma unroll
    for (int mt = 0; mt < 3; ++mt)
#pragma unroll
      for (int nt = 0; nt < 2; ++nt) {
        accr[mt][nt] = __builtin_amdgcn_mfma_f32_16x16x32_bf16(afc[mt][ks], bf[nt], accr[mt][nt], 0, 0, 0);
        acci[mt][nt] = __builtin_amdgcn_mfma_f32_16x16x32_bf16(afs[mt][ks], bf[nt], acci[mt][nt], 0, 0, 0);
      }
  }
#pragma unroll
  for (int arr = 0; arr < 2; ++arr) {
    __syncthreads();                // Xs dead after this point on arr=0
#pragma unroll
    for (int mt = 0; mt < 3; ++mt)
#pragma unroll
      for (int nt = 0; nt < 2; ++nt)
#pragma unroll
        for (int r = 0; r < 4; ++r) {
          int row = mt * 16 + lq * 4 + r;
          if (row <= 32) {           // rows 33..47 never stored — skip the LDS writes
            int col = w * 32 + nt * 16 + lm;
            float v = arr ? acci[mt][nt][r] : accr[mt][nt][r];
            Ep[row * 136 + col] = f2bf(v);
          }
        }
    __syncthreads();
    __hip_bfloat16* dst = arr ? Ai : Ar;
#pragma unroll
    for (int it = 0; it < 3; ++it) {
      int idx = it * 256 + t;       // uint4 units; keep rows <=32
      int row = idx >> 4, cq = (idx & 15) * 8;
      if (row <= 32) {
        uint4 v = *(const uint4*)&Ep[row * 136 + cq];
        *(uint4*)&dst[(size_t)(s * 64 + row) * 768 + c0 + cq] = v;
      }
    }
  }
}

// ---------- K3: by<6 = M gemm head; by>=6 = FFT pass B ----------
__global__ __launch_bounds__(256) void fft_b_mfma(const __hip_bfloat16* __restrict__ Ar,
                                                  const __hip_bfloat16* __restrict__ Ai,
                                                  __hip_bfloat16* __restrict__ Xf,
                                                  const ushort_t* __restrict__ TwB,
                                                  const ushort_t* __restrict__ Pb,
                                                  const ushort_t* __restrict__ Qb,
                                                  __hip_bfloat16* __restrict__ Mb) {
  __shared__ ushort_t smem[17408];    // 34816 B
  const int t = threadIdx.x;
  const int w = t >> 6, l = t & 63;

  if (blockIdx.y < 6) {               // ---------------- M = Pb @ Qb^T ----------------
    ushort_t* As = smem;              // [128][64]
    ushort_t* Bs = smem + 8192;
    const int m0 = blockIdx.y * 128;
    const int n0 = blockIdx.x * 128;
    const int wm = w & 1, wn = w >> 1;
    f32x16 acc[2][2] = {};
    const int srow = l >> 3;
    const int schunk = (l & 7) ^ srow;
    const int lr = l & 31, lh = l >> 5;
    for (int kt = 0; kt < 12; ++kt) {
      const int k0 = kt * 64;
#pragma unroll
      for (int i = 0; i < 4; ++i) {
        const int rbase = w * 32 + i * 8;
        const int row = rbase + srow;
        gl_lds16(&Pb[(size_t)(m0 + row) * 768 + k0 + schunk * 8], &As[rbase * 64]);
        gl_lds16(&Qb[(size_t)(n0 + row) * 768 + k0 + schunk * 8], &Bs[rbase * 64]);
      }
      __syncthreads();
#pragma unroll
      for (int ks = 0; ks < 4; ++ks) {
        bf16x8 af[2], bfv[2];
#pragma unroll
        for (int mt = 0; mt < 2; ++mt) {
          int row = wm * 64 + mt * 32 + lr;
          int ch = (ks * 2 + lh) ^ (lr & 7);
          af[mt] = *(const bf16x8*)&As[row * 64 + ch * 8];
        }
#pragma unroll
        for (int nt = 0; nt < 2; ++nt) {
          int row = wn * 64 + nt * 32 + lr;
          int ch = (ks * 2 + lh) ^ (lr & 7);
          bfv[nt] = *(const bf16x8*)&Bs[row * 64 + ch * 8];
        }
#pragma unroll
        for (int mt = 0; mt < 2; ++mt)
#pragma unroll
          for (int nt = 0; nt < 2; ++nt)
            acc[mt][nt] = __builtin_amdgcn_mfma_f32_32x32x16_bf16(af[mt], bfv[nt], acc[mt][nt], 0, 0, 0);
      }
      __syncthreads();
    }
#pragma unroll
    for (int nt = 0; nt < 2; ++nt) {
      const int col = n0 + wn * 64 + nt * 32 + lr;
#pragma unroll
      for (int mt = 0; mt < 2; ++mt) {
        const int rb = m0 + wm * 64 + mt * 32 + 4 * lh;
#pragma unroll
        for (int reg = 0; reg < 16; ++reg) {
          const int row = rb + (reg & 3) + 8 * (reg >> 2);
          Mb[(size_t)row * 768 + col] = __float2bfloat16(acc[mt][nt][reg]);
        }
      }
    }
    return;
  }

  // ---------------- FFT pass B ----------------
  ushort_t* Rs = smem;                // [c][d swz] stride 68
  ushort_t* Is = smem + 8704;
  ushort_t* Ep = smem;                // [k1][c] stride 136, after Rs dead
  const int bz = blockIdx.y - 6;      // b*33 + k2
  const int b = bz / 33, k2 = bz % 33;
  const int c0 = blockIdx.x * 128;
  const ushort_t* ar = (const ushort_t*)Ar + ((size_t)(b * 64) * 64 + k2) * 768 + c0;
  const ushort_t* ai = (const ushort_t*)Ai + ((size_t)(b * 64) * 64 + k2) * 768 + c0;
  const size_t n1s = (size_t)64 * 768;
  const int wm = w & 1, wn = w >> 1;
  const int lm = l & 15, lq = l >> 4;
  const bf16x8* twb = (const bf16x8*)TwB;
  bf16x8 afc[2][2], afs[2][2];
#pragma unroll
  for (int mt = 0; mt < 2; ++mt)
#pragma unroll
    for (int ks = 0; ks < 2; ++ks) {
      afc[mt][ks] = twb[wm * 256 + mt * 128 + ks * 64 + l];
      afs[mt][ks] = twb[512 + wm * 256 + mt * 128 + ks * 64 + l];
    }
  // Ar/Ai staging: dwordx2 loads, register repack, atom-swizzled LDS writes
#pragma unroll
  for (int it = 0; it < 4; ++it) {
    const int pr = it * 8 + (t >> 5);        // n1-pair dword 0..31
    const int c = (t & 31) * 4;
    const size_t o0 = (size_t)(2 * pr) * n1s + c;
    uint2 va = *(const uint2*)&ar[o0];
    uint2 vb = *(const uint2*)&ar[o0 + n1s];
    uint2 ia = *(const uint2*)&ai[o0];
    uint2 ib = *(const uint2*)&ai[o0 + n1s];
    uint_t rr[4], ss[4];
    rr[0] = (va.x & 0xffffu) | (vb.x << 16);
    rr[1] = (va.x >> 16) | (vb.x & 0xffff0000u);
    rr[2] = (va.y & 0xffffu) | (vb.y << 16);
    rr[3] = (va.y >> 16) | (vb.y & 0xffff0000u);
    ss[0] = (ia.x & 0xffffu) | (ib.x << 16);
    ss[1] = (ia.x >> 16) | (ib.x & 0xffff0000u);
    ss[2] = (ia.y & 0xffffu) | (ib.y << 16);
    ss[3] = (ia.y >> 16) | (ib.y & 0xffff0000u);
#pragma unroll
    for (int j = 0; j < 4; ++j) {
      const int row = c + j;
      const int d = pr ^ (((row >> 4) & 7) << 1);
      *(uint_t*)&Rs[row * 68 + 2 * d] = rr[j];
      *(uint_t*)&Is[row * 68 + 2 * d] = ss[j];
    }
  }
  __syncthreads();
  f32x4 accC[2][4] = {}, accS[2][4] = {};
#pragma unroll
  for (int ks = 0; ks < 2; ++ks) {
    bf16x8 bR[4], bI[4];
#pragma unroll
    for (int nt = 0; nt < 4; ++nt) {
      int c = wn * 64 + nt * 16 + lm;
      int sel2 = ((c >> 4) & 7) << 1;
      int D0 = ks * 16 + lq * 4;
      bR[nt] = ld_swz(&Rs[c * 68], D0, sel2);
      bI[nt] = ld_swz(&Is[c * 68], D0, sel2);
    }
#pragma unroll
    for (int mt = 0; mt < 2; ++mt)
#pragma unroll
      for (int nt = 0; nt < 4; ++nt) {
        accC[mt][nt] = __builtin_amdgcn_mfma_f32_16x16x32_bf16(afc[mt][ks], bR[nt], accC[mt][nt], 0, 0, 0);
        accS[mt][nt] = __builtin_amdgcn_mfma_f32_16x16x32_bf16(afs[mt][ks], bI[nt], accS[mt][nt], 0, 0, 0);
      }
  }
  const int nout = (k2 >= 1 && k2 <= 31) ? 2 : 1;
  for (int o = 0; o < nout; ++o) {
    __syncthreads();                   // Rs/Is dead from here
#pragma unroll
    for (int mt = 0; mt < 2; ++mt)
#pragma unroll
      for (int nt = 0; nt < 4; ++nt)
#pragma unroll
        for (int r = 0; r < 4; ++r) {
          int row = wm * 32 + mt * 16 + lq * 4 + r;   // k1
          int col = wn * 64 + nt * 16 + lm;           // c
          float v = o ? (accC[mt][nt][r] + accS[mt][nt][r])
                      : (accC[mt][nt][r] - accS[mt][nt][r]);
          Ep[row * 136 + col] = f2bf(v);
        }
    __syncthreads();
    const int k2o = o ? (64 - k2) : k2;
#pragma unroll
    for (int it = 0; it < 4; ++it) {
      int idx = it * 256 + t;
      int k1 = idx >> 4, cq = (idx & 15) * 8;
      uint4 v = *(const uint4*)&Ep[k1 * 136 + cq];
      *(uint4*)&Xf[((size_t)b * 4096 + k1 * 64 + k2o) * 768 + c0 + cq] = v;
    }
  }
}

// ---------- K4: Y[m,n] = sum_k Xf[m,k]*Mb[n,k] + bias[n] ----------
__global__ __launch_bounds__(256) void gemm_bt(const __hip_bfloat16* __restrict__ A,
                                               const __hip_bfloat16* __restrict__ B,
                                               const float* __restrict__ bias,
                                               float* __restrict__ C) {
  __shared__ ushort_t As[128 * 64];
  __shared__ ushort_t Bs[128 * 64];
  const int t = threadIdx.x, w = t >> 6, l = t & 63;
  const int L = blockIdx.x + blockIdx.y * 6;
  const int s = L >> 3, xcd = L & 7;
  const int n0 = (s % 6) * 128;
  const int m0 = ((s / 6) * 8 + xcd) * 128;
  const int wm = w & 1, wn = w >> 1;
  f32x16 acc[2][2] = {};
  const int srow = l >> 3;
  const int schunk = (l & 7) ^ srow;
  const int lr = l & 31, lh = l >> 5;
  for (int kt = 0; kt < 12; ++kt) {
    const int k0 = kt * 64;
#pragma unroll
    for (int i = 0; i < 4; ++i) {
      const int rbase = w * 32 + i * 8;
      const int row = rbase + srow;
      gl_lds16(&A[(size_t)(m0 + row) * 768 + k0 + schunk * 8], &As[rbase * 64]);
      gl_lds16(&B[(size_t)(n0 + row) * 768 + k0 + schunk * 8], &Bs[rbase * 64]);
    }
    __syncthreads();
#pragma unroll
    for (int ks = 0; ks < 4; ++ks) {
      bf16x8 af[2], bf[2];
#pragma unroll
      for (int mt = 0; mt < 2; ++mt) {
        int row = wm * 64 + mt * 32 + lr;
        int ch = (ks * 2 + lh) ^ (lr & 7);
        af[mt] = *(const bf16x8*)&As[row * 64 + ch * 8];
      }
#pragma unroll
      for (int nt = 0; nt < 2; ++nt) {
        int row = wn * 64 + nt * 32 + lr;
        int ch = (ks * 2 + lh) ^ (lr & 7);
        bf[nt] = *(const bf16x8*)&Bs[row * 64 + ch * 8];
      }
#pragma unroll
      for (int mt = 0; mt < 2; ++mt)
#pragma unroll
        for (int nt = 0; nt < 2; ++nt)
          acc[mt][nt] = __builtin_amdgcn_mfma_f32_32x32x16_bf16(af[mt], bf[nt], acc[mt][nt], 0, 0, 0);
    }
    __syncthreads();
  }
#pragma unroll
  for (int nt = 0; nt < 2; ++nt) {
    const int col = n0 + wn * 64 + nt * 32 + lr;
    const float bv = bias[col];
#pragma unroll
    for (int mt = 0; mt < 2; ++mt) {
      const int rb = m0 + wm * 64 + mt * 32 + 4 * lh;
#pragma unroll
      for (int reg = 0; reg < 16; ++reg) {
        const int row = rb + (reg & 3) + 8 * (reg >> 2);
        C[(size_t)row * 768 + col] = acc[mt][nt][reg] + bv;
      }
    }
  }
}

extern "C" void kernel_launch(void* const* d_in, const int* in_sizes, int n_in,
                              void* d_out, int out_size, void* d_ws, size_t ws_size,
                              hipStream_t stream) {
  const float* x      = (const float*)d_in[0];  // [8,4096,768]
  const float* qkv_w  = (const float*)d_in[1];  // [2304,768]
  const float* proj_w = (const float*)d_in[2];  // [768,768]
  const float* proj_b = (const float*)d_in[3];  // [768]
  float* out = (float*)d_out;                   // [8,4096,768] fp32

  char* ws = (char*)d_ws;
  const size_t MB_BYTES = (size_t)768 * 768 * 2;
  const size_t ARR_BYTES = (size_t)8 * 4096 * 768 * 2;
  __hip_bfloat16* Mb = (__hip_bfloat16*)ws;
  __hip_bfloat16* Ar = (__hip_bfloat16*)(ws + MB_BYTES);
  __hip_bfloat16* Ai = (__hip_bfloat16*)(ws + MB_BYTES + ARR_BYTES);
  __hip_bfloat16* Xf = (__hip_bfloat16*)(ws + MB_BYTES + 2 * ARR_BYTES);
  ushort_t* Pb = (ushort_t*)(ws + MB_BYTES + 3 * ARR_BYTES);             // 1.125 MB
  ushort_t* Qb = (ushort_t*)(ws + MB_BYTES + 3 * ARR_BYTES + MB_BYTES);  // 1.125 MB
  // Twiddle tables live in dead rows (k2=40..63 of s=0 block) of Ar:
  // fft_a only writes rows <=32 per 64-row group; fft_b only reads k2<=32.
  ushort_t* TwA = (ushort_t*)((char*)Ar + 61440);            // 12288 B
  ushort_t* TwB = (ushort_t*)((char*)Ar + 61440 + 12288);    // 16384 B

  prep<<<dim3(439), 256, 0, stream>>>(proj_w, qkv_w, TwA, TwB, Pb, Qb);
  fft_a_pre<<<dim3(6, 512), 256, 0, stream>>>(x, Ar, Ai, TwA);
  fft_b_mfma<<<dim3(6, 270), 256, 0, stream>>>(Ar, Ai, Xf, TwB, Pb, Qb, Mb);
  gemm_bt<<<dim3(6, 256), 256, 0, stream>>>(Xf, Mb, proj_b, out);
}

// Round 3
// 251.972 us; speedup vs baseline: 1.1208x; 1.0129x over previous
//
#include <hip/hip_runtime.h>
#include <hip/hip_bf16.h>

// B=8, N=4096 (=64x64 spatial), C=768.
// Y = ReFFT2_spatial(X) @ (proj_w @ Wv)^T + proj_b,  Wv = qkv_w[1536:2304].
// K0 prep: twiddle fragment tables + Pb (bf16 proj_w) + Qb (bf16 Wv^T)
// K2: pass A twiddle-MFMA, 2 s-groups/block, Hermitian store k2=0..32
// K3: by<6 = M = Pb @ Qb^T; else FFT pass B, 2 k2/block (shared twiddles)
// K4: Y = Xf @ M^T + b   (32x32x16 MFMA, BK=64, XOR-swizzled staging)

typedef __bf16 bf16x8 __attribute__((ext_vector_type(8)));
typedef __bf16 bf16x4 __attribute__((ext_vector_type(4)));
typedef float f32x4 __attribute__((ext_vector_type(4)));
typedef float f32x16 __attribute__((ext_vector_type(16)));
typedef unsigned short ushort_t;
typedef unsigned int uint_t;

typedef __attribute__((address_space(3))) unsigned int lds_u32;
typedef __attribute__((address_space(1))) unsigned int glob_u32;

__device__ __forceinline__ void gl_lds16(const void* g, void* l) {
  __builtin_amdgcn_global_load_lds((const glob_u32*)g, (lds_u32*)l, 16, 0, 0);
}

__device__ __forceinline__ ushort_t f2bf(float f) {
  union { __hip_bfloat16 h; ushort_t s; } cv;
  cv.h = __float2bfloat16(f);
  return cv.s;
}

__device__ __forceinline__ bf16x8 ld_frag(const ushort_t* p) {  // 8B-aligned
  union { bf16x8 v; bf16x4 h[2]; } r;
  r.h[0] = *(const bf16x4*)p;
  r.h[1] = *(const bf16x4*)(p + 4);
  return r.v;
}

// Swizzled fragment read: row-major [row][dword d] with d stored at d^sel2.
__device__ __forceinline__ bf16x8 ld_swz(const ushort_t* rowp, int D0, int sel2) {
  union { bf16x8 v; bf16x4 h[2]; } r;
  r.h[0] = *(const bf16x4*)(rowp + 2 * (D0 ^ sel2));
  r.h[1] = *(const bf16x4*)(rowp + 2 * ((D0 + 2) ^ sel2));
  return r.v;
}

// ---------- K0: twiddle tables + bf16 weight prep ----------
__global__ __launch_bounds__(256) void prep(const float* __restrict__ P,
                                            const float* __restrict__ Q,
                                            ushort_t* __restrict__ TwA,
                                            ushort_t* __restrict__ TwB,
                                            ushort_t* __restrict__ Pb,
                                            ushort_t* __restrict__ Qb) {
  __shared__ ushort_t Ts[4608];                  // 64x72 transpose tile
  const int t = threadIdx.x;
  if (blockIdx.x < 7) {                          // ---- twiddle tables ----
    const int id = blockIdx.x * 256 + t;         // 0..1791
    int m, k0, sn;
    ushort_t* out;
    if (id < 768) {
      int r = id % 384, cs = id / 384;
      int l = r & 63, ks = (r >> 6) & 1, mt = r >> 7;
      m = mt * 16 + (l & 15);
      k0 = ks * 32 + (l >> 4) * 8;
      sn = cs;
      out = TwA + id * 8;
    } else {
      int j = id - 768;
      int r = j % 512, cs = j / 512;
      int l = r & 63, ks = (r >> 6) & 1, mt = (r >> 7) & 1, wm = r >> 8;
      m = wm * 32 + mt * 16 + (l & 15);
      k0 = ks * 32 + (l >> 4) * 8;
      sn = cs;
      out = TwB + j * 8;
    }
#pragma unroll
    for (int e = 0; e < 8; ++e) {
      int ph = (m * (k0 + e)) & 63;
      float a = (float)ph * 0.09817477042468104f;  // 2*pi/64
      out[e] = f2bf(sn ? __sinf(a) : __cosf(a));
    }
  } else if (blockIdx.x < 151) {                 // ---- Qb transpose (144 tiles) ----
    const int tile = blockIdx.x - 7;
    const int ti = tile / 12, tj = tile % 12;
    const int r0 = t >> 4, c4 = (t & 15) * 4;
#pragma unroll
    for (int rr = 0; rr < 4; ++rr) {
      const int k = ti * 64 + r0 + rr * 16;
      f32x4 v = *(const f32x4*)&Q[(size_t)(1536 + k) * 768 + tj * 64 + c4];
#pragma unroll
      for (int j = 0; j < 4; ++j)
        Ts[(c4 + j) * 72 + r0 + rr * 16] = f2bf(v[j]);
    }
    __syncthreads();
    const int co = t >> 2, kq = (t & 3) * 16;
    uint4 v0 = *(const uint4*)&Ts[co * 72 + kq];
    uint4 v1 = *(const uint4*)&Ts[co * 72 + kq + 8];
    ushort_t* dst = Qb + (size_t)(tj * 64 + co) * 768 + ti * 64 + kq;
    *(uint4*)&dst[0] = v0;
    *(uint4*)&dst[8] = v1;
  } else {                                       // ---- Pb convert (288 blocks) ----
    const int cid = blockIdx.x - 151;
    const size_t off = (size_t)cid * 2048 + t * 8;
    f32x4 f0 = *(const f32x4*)&P[off];
    f32x4 f1 = *(const f32x4*)&P[off + 4];
    union { ushort_t u[8]; uint4 v; } pk;
#pragma unroll
    for (int j = 0; j < 4; ++j) { pk.u[j] = f2bf(f0[j]); pk.u[4 + j] = f2bf(f1[j]); }
    *(uint4*)&Pb[off] = pk.v;
  }
}

// ---------- K2: FFT pass A, 2 s-groups per block ----------
__global__ __launch_bounds__(256) void fft_a_pre(const float* __restrict__ X,
                                                 __hip_bfloat16* __restrict__ Ar,
                                                 __hip_bfloat16* __restrict__ Ai,
                                                 const ushort_t* __restrict__ TwA) {
  __shared__ ushort_t smem[17408];    // 34816B: Xs0|Xs1 (8704 ush each); Ep2 (13056) overlays
  const int t = threadIdx.x;
  const int c0 = blockIdx.x * 128;
  const int w = t >> 6, l = t & 63;
  const int lm = l & 15, lq = l >> 4;
  const int s0 = blockIdx.y * 2;
  const bf16x8* twa = (const bf16x8*)TwA;
  bf16x8 afc[3][2], afs[3][2];
#pragma unroll
  for (int mt = 0; mt < 3; ++mt)
#pragma unroll
    for (int ks = 0; ks < 2; ++ks) {
      afc[mt][ks] = twa[mt * 128 + ks * 64 + l];
      afs[mt][ks] = twa[384 + mt * 128 + ks * 64 + l];
    }
  // Stage both s-groups: 16 dwordx4 loads in flight, swizzled LDS writes
#pragma unroll
  for (int ss = 0; ss < 2; ++ss) {
    ushort_t* Xs = smem + ss * 8704;
    const float* src = X + (size_t)(s0 + ss) * 64 * 768 + c0;
#pragma unroll
    for (int it = 0; it < 4; ++it) {
      const int pr = it * 8 + (t >> 5);        // n2-pair dword 0..31
      const int c = (t & 31) * 4;
      const float* rp = src + (size_t)(2 * pr) * 768 + c;
      f32x4 f0 = *(const f32x4*)rp;
      f32x4 f1 = *(const f32x4*)(rp + 768);
#pragma unroll
      for (int j = 0; j < 4; ++j) {
        uint_t pk = (uint_t)f2bf(f0[j]) | ((uint_t)f2bf(f1[j]) << 16);
        const int row = c + j;
        const int d = pr ^ (((row >> 4) & 7) << 1);
        *(uint_t*)&Xs[row * 68 + 2 * d] = pk;
      }
    }
  }
  __syncthreads();
  f32x4 accr[2][3][2] = {}, acci[2][3][2] = {};
#pragma unroll
  for (int ss = 0; ss < 2; ++ss) {
    const ushort_t* Xs = smem + ss * 8704;
#pragma unroll
    for (int ks = 0; ks < 2; ++ks) {
      bf16x8 bf[2];
#pragma unroll
      for (int nt = 0; nt < 2; ++nt) {
        int c = w * 32 + nt * 16 + lm;
        int sel2 = ((c >> 4) & 7) << 1;
        bf[nt] = ld_swz(&Xs[c * 68], ks * 16 + lq * 4, sel2);
      }
#pragma unroll
      for (int mt = 0; mt < 3; ++mt)
#pragma unroll
        for (int nt = 0; nt < 2; ++nt) {
          accr[ss][mt][nt] = __builtin_amdgcn_mfma_f32_16x16x32_bf16(afc[mt][ks], bf[nt], accr[ss][mt][nt], 0, 0, 0);
          acci[ss][mt][nt] = __builtin_amdgcn_mfma_f32_16x16x32_bf16(afs[mt][ks], bf[nt], acci[ss][mt][nt], 0, 0, 0);
        }
    }
  }
  // Epilogue: per s-group, re+im in one double-Ep phase (all Xs dead now)
#pragma unroll
  for (int ss = 0; ss < 2; ++ss) {
    __syncthreads();
#pragma unroll
    for (int arr = 0; arr < 2; ++arr)
#pragma unroll
      for (int mt = 0; mt < 3; ++mt)
#pragma unroll
        for (int nt = 0; nt < 2; ++nt)
#pragma unroll
          for (int r = 0; r < 4; ++r) {
            int row = mt * 16 + lq * 4 + r;
            if (row <= 32) {
              int col = w * 32 + nt * 16 + lm;
              float v = arr ? acci[ss][mt][nt][r] : accr[ss][mt][nt][r];
              smem[arr * 6528 + row * 136 + col] = f2bf(v);
            }
          }
    __syncthreads();
#pragma unroll
    for (int it = 0; it < 5; ++it) {
      int idx = it * 256 + t;                  // 2 arrays x 33 rows x 16 chunks = 1056
      if (idx < 1056) {
        int arr = idx >= 528 ? 1 : 0;
        int rem = idx - arr * 528;
        int row = rem >> 4, cq = (rem & 15) * 8;
        uint4 v = *(const uint4*)&smem[arr * 6528 + row * 136 + cq];
        __hip_bfloat16* dst = arr ? Ai : Ar;
        *(uint4*)&dst[(size_t)((s0 + ss) * 64 + row) * 768 + c0 + cq] = v;
      }
    }
  }
}

// ---------- K3: by<6 = M gemm head; else FFT pass B, 2 k2 per block ----------
__global__ __launch_bounds__(256) void fft_b_mfma(const __hip_bfloat16* __restrict__ Ar,
                                                  const __hip_bfloat16* __restrict__ Ai,
                                                  __hip_bfloat16* __restrict__ Xf,
                                                  const ushort_t* __restrict__ TwB,
                                                  const ushort_t* __restrict__ Pb,
                                                  const ushort_t* __restrict__ Qb,
                                                  __hip_bfloat16* __restrict__ Mb) {
  __shared__ ushort_t smem[34816];    // 69632B: region[2] x {Rs 8704 | Is 8704}; Ep2 overlays region
  const int t = threadIdx.x;
  const int w = t >> 6, l = t & 63;

  if (blockIdx.y < 6) {               // ---------------- M = Pb @ Qb^T ----------------
    ushort_t* As = smem;
    ushort_t* Bs = smem + 8192;
    const int m0 = blockIdx.y * 128;
    const int n0 = blockIdx.x * 128;
    const int wm = w & 1, wn = w >> 1;
    f32x16 acc[2][2] = {};
    const int srow = l >> 3;
    const int schunk = (l & 7) ^ srow;
    const int lr = l & 31, lh = l >> 5;
    for (int kt = 0; kt < 12; ++kt) {
      const int k0 = kt * 64;
#pragma unroll
      for (int i = 0; i < 4; ++i) {
        const int rbase = w * 32 + i * 8;
        const int row = rbase + srow;
        gl_lds16(&Pb[(size_t)(m0 + row) * 768 + k0 + schunk * 8], &As[rbase * 64]);
        gl_lds16(&Qb[(size_t)(n0 + row) * 768 + k0 + schunk * 8], &Bs[rbase * 64]);
      }
      __syncthreads();
#pragma unroll
      for (int ks = 0; ks < 4; ++ks) {
        bf16x8 af[2], bfv[2];
#pragma unroll
        for (int mt = 0; mt < 2; ++mt) {
          int row = wm * 64 + mt * 32 + lr;
          int ch = (ks * 2 + lh) ^ (lr & 7);
          af[mt] = *(const bf16x8*)&As[row * 64 + ch * 8];
        }
#pragma unroll
        for (int nt = 0; nt < 2; ++nt) {
          int row = wn * 64 + nt * 32 + lr;
          int ch = (ks * 2 + lh) ^ (lr & 7);
          bfv[nt] = *(const bf16x8*)&Bs[row * 64 + ch * 8];
        }
#pragma unroll
        for (int mt = 0; mt < 2; ++mt)
#pragma unroll
          for (int nt = 0; nt < 2; ++nt)
            acc[mt][nt] = __builtin_amdgcn_mfma_f32_32x32x16_bf16(af[mt], bfv[nt], acc[mt][nt], 0, 0, 0);
      }
      __syncthreads();
    }
#pragma unroll
    for (int nt = 0; nt < 2; ++nt) {
      const int col = n0 + wn * 64 + nt * 32 + lr;
#pragma unroll
      for (int mt = 0; mt < 2; ++mt) {
        const int rb = m0 + wm * 64 + mt * 32 + 4 * lh;
#pragma unroll
        for (int reg = 0; reg < 16; ++reg) {
          const int row = rb + (reg & 3) + 8 * (reg >> 2);
          Mb[(size_t)row * 768 + col] = __float2bfloat16(acc[mt][nt][reg]);
        }
      }
    }
    return;
  }

  // ---------------- FFT pass B: k2 pair {kp, kp+16} (kp==16 -> {32}) ----------------
  const int bz = blockIdx.y - 6;      // b*17 + kp
  const int b = bz / 17, kp = bz % 17;
  const int nk = (kp == 16) ? 1 : 2;
  const int k2v0 = (kp == 16) ? 32 : kp;
  const int k2v1 = kp + 16;
  const int c0 = blockIdx.x * 128;
  const size_t n1s = (size_t)64 * 768;
  const int wm = w & 1, wn = w >> 1;
  const int lm = l & 15, lq = l >> 4;
  const bf16x8* twb = (const bf16x8*)TwB;
  bf16x8 afc[2][2], afs[2][2];        // shared across both k2 (twiddles depend on k1,n1 only)
#pragma unroll
  for (int mt = 0; mt < 2; ++mt)
#pragma unroll
    for (int ks = 0; ks < 2; ++ks) {
      afc[mt][ks] = twb[wm * 256 + mt * 128 + ks * 64 + l];
      afs[mt][ks] = twb[512 + wm * 256 + mt * 128 + ks * 64 + l];
    }

  auto stage = [&](int kk, int k2) {
    ushort_t* Rs = smem + kk * 17408;
    ushort_t* Is = Rs + 8704;
    const ushort_t* ar = (const ushort_t*)Ar + ((size_t)(b * 64) * 64 + k2) * 768 + c0;
    const ushort_t* ai = (const ushort_t*)Ai + ((size_t)(b * 64) * 64 + k2) * 768 + c0;
#pragma unroll
    for (int it = 0; it < 4; ++it) {
      const int pr = it * 8 + (t >> 5);
      const int c = (t & 31) * 4;
      const size_t o0 = (size_t)(2 * pr) * n1s + c;
      uint2 va = *(const uint2*)&ar[o0];
      uint2 vb = *(const uint2*)&ar[o0 + n1s];
      uint2 ia = *(const uint2*)&ai[o0];
      uint2 ib = *(const uint2*)&ai[o0 + n1s];
      uint_t rr[4], ss_[4];
      rr[0] = (va.x & 0xffffu) | (vb.x << 16);
      rr[1] = (va.x >> 16) | (vb.x & 0xffff0000u);
      rr[2] = (va.y & 0xffffu) | (vb.y << 16);
      rr[3] = (va.y >> 16) | (vb.y & 0xffff0000u);
      ss_[0] = (ia.x & 0xffffu) | (ib.x << 16);
      ss_[1] = (ia.x >> 16) | (ib.x & 0xffff0000u);
      ss_[2] = (ia.y & 0xffffu) | (ib.y << 16);
      ss_[3] = (ia.y >> 16) | (ib.y & 0xffff0000u);
#pragma unroll
      for (int j = 0; j < 4; ++j) {
        const int row = c + j;
        const int d = pr ^ (((row >> 4) & 7) << 1);
        *(uint_t*)&Rs[row * 68 + 2 * d] = rr[j];
        *(uint_t*)&Is[row * 68 + 2 * d] = ss_[j];
      }
    }
  };

  auto do_mfma = [&](int kk, f32x4 (&aC)[2][4], f32x4 (&aS)[2][4]) {
    const ushort_t* Rs = smem + kk * 17408;
    const ushort_t* Is = Rs + 8704;
#pragma unroll
    for (int ks = 0; ks < 2; ++ks) {
      bf16x8 bR[4], bI[4];
#pragma unroll
      for (int nt = 0; nt < 4; ++nt) {
        int c = wn * 64 + nt * 16 + lm;
        int sel2 = ((c >> 4) & 7) << 1;
        int D0 = ks * 16 + lq * 4;
        bR[nt] = ld_swz(&Rs[c * 68], D0, sel2);
        bI[nt] = ld_swz(&Is[c * 68], D0, sel2);
      }
#pragma unroll
      for (int mt = 0; mt < 2; ++mt)
#pragma unroll
        for (int nt = 0; nt < 4; ++nt) {
          aC[mt][nt] = __builtin_amdgcn_mfma_f32_16x16x32_bf16(afc[mt][ks], bR[nt], aC[mt][nt], 0, 0, 0);
          aS[mt][nt] = __builtin_amdgcn_mfma_f32_16x16x32_bf16(afs[mt][ks], bI[nt], aS[mt][nt], 0, 0, 0);
        }
    }
  };

  auto ep_write = [&](int kk, int nout, f32x4 (&aC)[2][4], f32x4 (&aS)[2][4]) {
    ushort_t* Ep = smem + kk * 17408;          // [o][64][136], overlays region kk
    for (int o = 0; o < nout; ++o)
#pragma unroll
      for (int mt = 0; mt < 2; ++mt)
#pragma unroll
        for (int nt = 0; nt < 4; ++nt)
#pragma unroll
          for (int r = 0; r < 4; ++r) {
            int row = wm * 32 + mt * 16 + lq * 4 + r;
            int col = wn * 64 + nt * 16 + lm;
            float v = o ? (aC[mt][nt][r] + aS[mt][nt][r])
                        : (aC[mt][nt][r] - aS[mt][nt][r]);
            Ep[o * 8704 + row * 136 + col] = f2bf(v);
          }
  };

  auto gout = [&](int kk, int k2, int nout) {
    const ushort_t* Ep = smem + kk * 17408;
#pragma unroll
    for (int it = 0; it < 8; ++it) {
      int idx = it * 256 + t;
      if (idx < nout * 1024) {
        int o = idx >> 10, rem = idx & 1023;
        int k1 = rem >> 4, cq = (rem & 15) * 8;
        uint4 v = *(const uint4*)&Ep[o * 8704 + k1 * 136 + cq];
        int k2o = o ? (64 - k2) : k2;
        *(uint4*)&Xf[((size_t)b * 4096 + k1 * 64 + k2o) * 768 + c0 + cq] = v;
      }
    }
  };

  const int nout0 = (k2v0 >= 1 && k2v0 <= 31) ? 2 : 1;
  stage(0, k2v0);
  if (nk == 2) stage(1, k2v1);
  __syncthreads();
  {
    f32x4 aC[2][4] = {}, aS[2][4] = {};
    do_mfma(0, aC, aS);
    __syncthreads();                   // all waves done reading region 0
    ep_write(0, nout0, aC, aS);
  }
  __syncthreads();
  if (nk == 2) {
    f32x4 aC[2][4] = {}, aS[2][4] = {};
    do_mfma(1, aC, aS);                // region 1 untouched so far
    gout(0, k2v0, nout0);              // reads region-0 Ep concurrently — disjoint
    __syncthreads();                   // all waves done reading region 1 + region-0 Ep
    ep_write(1, 2, aC, aS);            // k2v1 in 16..31 -> always 2 outputs
    __syncthreads();
    gout(1, k2v1, 2);
  } else {
    gout(0, k2v0, nout0);
  }
}

// ---------- K4: Y[m,n] = sum_k Xf[m,k]*Mb[n,k] + bias[n] ----------
__global__ __launch_bounds__(256) void gemm_bt(const __hip_bfloat16* __restrict__ A,
                                               const __hip_bfloat16* __restrict__ B,
                                               const float* __restrict__ bias,
                                               float* __restrict__ C) {
  __shared__ ushort_t As[128 * 64];
  __shared__ ushort_t Bs[128 * 64];
  const int t = threadIdx.x, w = t >> 6, l = t & 63;
  const int L = blockIdx.x + blockIdx.y * 6;
  const int s = L >> 3, xcd = L & 7;
  const int n0 = (s % 6) * 128;
  const int m0 = ((s / 6) * 8 + xcd) * 128;
  const int wm = w & 1, wn = w >> 1;
  f32x16 acc[2][2] = {};
  const int srow = l >> 3;
  const int schunk = (l & 7) ^ srow;
  const int lr = l & 31, lh = l >> 5;
  for (int kt = 0; kt < 12; ++kt) {
    const int k0 = kt * 64;
#pragma unroll
    for (int i = 0; i < 4; ++i) {
      const int rbase = w * 32 + i * 8;
      const int row = rbase + srow;
      gl_lds16(&A[(size_t)(m0 + row) * 768 + k0 + schunk * 8], &As[rbase * 64]);
      gl_lds16(&B[(size_t)(n0 + row) * 768 + k0 + schunk * 8], &Bs[rbase * 64]);
    }
    __syncthreads();
#pragma unroll
    for (int ks = 0; ks < 4; ++ks) {
      bf16x8 af[2], bf[2];
#pragma unroll
      for (int mt = 0; mt < 2; ++mt) {
        int row = wm * 64 + mt * 32 + lr;
        int ch = (ks * 2 + lh) ^ (lr & 7);
        af[mt] = *(const bf16x8*)&As[row * 64 + ch * 8];
      }
#pragma unroll
      for (int nt = 0; nt < 2; ++nt) {
        int row = wn * 64 + nt * 32 + lr;
        int ch = (ks * 2 + lh) ^ (lr & 7);
        bf[nt] = *(const bf16x8*)&Bs[row * 64 + ch * 8];
      }
#pragma unroll
      for (int mt = 0; mt < 2; ++mt)
#pragma unroll
        for (int nt = 0; nt < 2; ++nt)
          acc[mt][nt] = __builtin_amdgcn_mfma_f32_32x32x16_bf16(af[mt], bf[nt], acc[mt][nt], 0, 0, 0);
    }
    __syncthreads();
  }
#pragma unroll
  for (int nt = 0; nt < 2; ++nt) {
    const int col = n0 + wn * 64 + nt * 32 + lr;
    const float bv = bias[col];
#pragma unroll
    for (int mt = 0; mt < 2; ++mt) {
      const int rb = m0 + wm * 64 + mt * 32 + 4 * lh;
#pragma unroll
      for (int reg = 0; reg < 16; ++reg) {
        const int row = rb + (reg & 3) + 8 * (reg >> 2);
        C[(size_t)row * 768 + col] = acc[mt][nt][reg] + bv;
      }
    }
  }
}

extern "C" void kernel_launch(void* const* d_in, const int* in_sizes, int n_in,
                              void* d_out, int out_size, void* d_ws, size_t ws_size,
                              hipStream_t stream) {
  const float* x      = (const float*)d_in[0];  // [8,4096,768]
  const float* qkv_w  = (const float*)d_in[1];  // [2304,768]
  const float* proj_w = (const float*)d_in[2];  // [768,768]
  const float* proj_b = (const float*)d_in[3];  // [768]
  float* out = (float*)d_out;                   // [8,4096,768] fp32

  char* ws = (char*)d_ws;
  const size_t MB_BYTES = (size_t)768 * 768 * 2;
  const size_t ARR_BYTES = (size_t)8 * 4096 * 768 * 2;
  __hip_bfloat16* Mb = (__hip_bfloat16*)ws;
  __hip_bfloat16* Ar = (__hip_bfloat16*)(ws + MB_BYTES);
  __hip_bfloat16* Ai = (__hip_bfloat16*)(ws + MB_BYTES + ARR_BYTES);
  __hip_bfloat16* Xf = (__hip_bfloat16*)(ws + MB_BYTES + 2 * ARR_BYTES);
  ushort_t* Pb = (ushort_t*)(ws + MB_BYTES + 3 * ARR_BYTES);             // 1.125 MB
  ushort_t* Qb = (ushort_t*)(ws + MB_BYTES + 3 * ARR_BYTES + MB_BYTES);  // 1.125 MB
  // Twiddle tables live in dead rows (k2=40..63 of s=0 block) of Ar.
  ushort_t* TwA = (ushort_t*)((char*)Ar + 61440);            // 12288 B
  ushort_t* TwB = (ushort_t*)((char*)Ar + 61440 + 12288);    // 16384 B

  prep<<<dim3(439), 256, 0, stream>>>(proj_w, qkv_w, TwA, TwB, Pb, Qb);
  fft_a_pre<<<dim3(6, 256), 256, 0, stream>>>(x, Ar, Ai, TwA);
  fft_b_mfma<<<dim3(6, 142), 256, 0, stream>>>(Ar, Ai, Xf, TwB, Pb, Qb, Mb);
  gemm_bt<<<dim3(6, 256), 256, 0, stream>>>(Xf, Mb, proj_b, out);
}